// Round 1
// baseline (282.929 us; speedup 1.0000x reference)
//
#include <hip/hip_runtime.h>
#include <math.h>

#define NSITES 27
#define NMID   25
#define DD     32

// One wave per MPS chain.
// Site tensor layout (per chain, per mid site): [d=32][p=2][e=32] fp32 (2048 floats).
// float4 index f = lane + 64*k  ->  d = (lane>>4)+4k, p = (lane>>3)&1, e = 4*(lane&7).
__global__ __launch_bounds__(64) void mps_layer_kernel(
    const float* __restrict__ src,    // cube of side 3*B, strides (9B*B, 3B, 1)
    const float* __restrict__ first,  // (N,2,1,32)
    const float* __restrict__ mid,    // (N,25,32,2,32)
    const float* __restrict__ last,   // (N,32,2)
    float*       __restrict__ out,    // (N)
    int B, int nChains)
{
    const int lane = threadIdx.x;
    const int n = blockIdx.x;
    if (n >= nChains) return;

    __shared__ float  sE[NSITES][2];
    __shared__ float4 sV4[8];
    float* sV = (float*)sV4;

    const int S = 3 * B;
    const int bh = n / (B * B);
    const int bv = (n / B) % B;
    const int bd = n % B;

    // ---- embeddings: lanes 0..26 each handle one site ----
    if (lane < NSITES) {
        const int kh = lane / 9, kv = (lane / 3) % 3, kd = lane % 3;
        const float x = src[(size_t)(bh*3 + kh) * S * S + (bv*3 + kv) * S + (bd*3 + kd)];
        float sn, cs;
        sincosf(1.5707963267948966f * x, &sn, &cs);
        sE[lane][0] = cs;
        sE[lane][1] = sn;
    }

    // ---- v0 from site 0 ----
    if (lane < DD) {
        const float* f = first + (size_t)n * (2 * DD);
        sV[lane] = fmaf(f[lane], sE[0][0], f[DD + lane] * sE[0][1]);
    }

    const int p     = (lane >> 3) & 1;
    const int e4    = lane & 7;
    const int dbase = lane >> 4;
    const float4* m4 = (const float4*)(mid + (size_t)n * NMID * 2048) + lane;

    // prefetch site 0's mid tensor
    float4 buf[8];
#pragma unroll
    for (int k = 0; k < 8; ++k) buf[k] = m4[64 * k];

    for (int m = 0; m < NMID; ++m) {
        float4 nxt[8];
        if (m + 1 < NMID) {
            const float4* m4n = m4 + (size_t)(m + 1) * 512;
#pragma unroll
            for (int k = 0; k < 8; ++k) nxt[k] = m4n[64 * k];
        }

        const float e0 = sE[m + 1][0];
        const float e1 = sE[m + 1][1];

        float4 acc; acc.x = acc.y = acc.z = acc.w = 0.f;
#pragma unroll
        for (int k = 0; k < 8; ++k) {
            const float vd = sV[dbase + 4 * k];
            acc.x = fmaf(buf[k].x, vd, acc.x);
            acc.y = fmaf(buf[k].y, vd, acc.y);
            acc.z = fmaf(buf[k].z, vd, acc.z);
            acc.w = fmaf(buf[k].w, vd, acc.w);
        }
        // reduce partial-d groups (lanes differing in bits 4,5)
#pragma unroll
        for (int mask = 16; mask <= 32; mask <<= 1) {
            acc.x += __shfl_xor(acc.x, mask, 64);
            acc.y += __shfl_xor(acc.y, mask, 64);
            acc.z += __shfl_xor(acc.z, mask, 64);
            acc.w += __shfl_xor(acc.w, mask, 64);
        }
        // combine the two phys components (partner lane differs in bit 3)
        float4 oth;
        oth.x = __shfl_xor(acc.x, 8, 64);
        oth.y = __shfl_xor(acc.y, 8, 64);
        oth.z = __shfl_xor(acc.z, 8, 64);
        oth.w = __shfl_xor(acc.w, 8, 64);
        const float cm = p ? e1 : e0;
        const float co = p ? e0 : e1;
        float4 nv;
        nv.x = fmaf(cm, acc.x, co * oth.x);
        nv.y = fmaf(cm, acc.y, co * oth.y);
        nv.z = fmaf(cm, acc.z, co * oth.z);
        nv.w = fmaf(cm, acc.w, co * oth.w);
        if (lane < 8) sV4[lane] = nv;   // lanes 0..7: p=0, e4=lane -> v[4*lane..]

#pragma unroll
        for (int k = 0; k < 8; ++k) buf[k] = nxt[k];
    }

    // ---- last site ----
    const float le0 = sE[26][0], le1 = sE[26][1];
    float t = 0.f;
    if (lane < DD) {
        const float* L = last + (size_t)n * (DD * 2);
        t = sV[lane] * fmaf(L[2 * lane], le0, L[2 * lane + 1] * le1);
    }
#pragma unroll
    for (int mask = 1; mask < 64; mask <<= 1) t += __shfl_xor(t, mask, 64);
    if (lane == 0) out[n] = t;
}

// Final layer: output leg (O=10) sits on site 0, so contract right-to-left:
// u = last·e26; u <- M_m u (m = 25..1); out[o] = sum_{p,d} ffirst[p][o][d] e0_p u[d].
__global__ __launch_bounds__(64) void mps_final_kernel(
    const float* __restrict__ x,       // out1 (27)
    const float* __restrict__ ffirst,  // (2,10,32)
    const float* __restrict__ fmid,    // (25,32,2,32)
    const float* __restrict__ flast,   // (32,2)
    float*       __restrict__ out)     // (10)
{
    const int lane = threadIdx.x;
    __shared__ float sE[NSITES][2];
    __shared__ float sU[DD];

    if (lane < NSITES) {
        float sn, cs;
        sincosf(1.5707963267948966f * x[lane], &sn, &cs);
        sE[lane][0] = cs;
        sE[lane][1] = sn;
    }
    if (lane < DD) {
        sU[lane] = fmaf(flast[2 * lane], sE[26][0], flast[2 * lane + 1] * sE[26][1]);
    }

    const int p     = (lane >> 3) & 1;
    const int e4    = lane & 7;
    const int dbase = lane >> 4;
    const float4* m4 = (const float4*)fmid + lane;

    for (int m = NMID - 1; m >= 0; --m) {
        const float e0 = sE[m + 1][0];
        const float e1 = sE[m + 1][1];
        const float ep = p ? e1 : e0;
        const float4* mm = m4 + (size_t)m * 512;

        const float4 u4 = ((const float4*)sU)[e4];
        const float wx = ep * u4.x, wy = ep * u4.y, wz = ep * u4.z, ww = ep * u4.w;

        float acc[8];
#pragma unroll
        for (int k = 0; k < 8; ++k) {
            const float4 Mv = mm[64 * k];
            acc[k] = fmaf(Mv.x, wx, fmaf(Mv.y, wy, fmaf(Mv.z, wz, Mv.w * ww)));
        }
        // full u'[d] needs sum over the 16 lanes sharing (lane>>4)
#pragma unroll
        for (int mask = 1; mask <= 8; mask <<= 1) {
#pragma unroll
            for (int k = 0; k < 8; ++k) acc[k] += __shfl_xor(acc[k], mask, 64);
        }
        if ((lane & 15) == 0) {
#pragma unroll
            for (int k = 0; k < 8; ++k) sU[dbase + 4 * k] = acc[k];
        }
    }

    const float e0 = sE[0][0], e1 = sE[0][1];
    const float ud = (lane < DD) ? sU[lane] : 0.f;
#pragma unroll
    for (int o = 0; o < 10; ++o) {
        float t = 0.f;
        if (lane < DD)
            t = fmaf(ffirst[o * DD + lane], e0, ffirst[320 + o * DD + lane] * e1) * ud;
#pragma unroll
        for (int mask = 1; mask < 64; mask <<= 1) t += __shfl_xor(t, mask, 64);
        if (lane == 0) out[o] = t;
    }
}

extern "C" void kernel_launch(void* const* d_in, const int* in_sizes, int n_in,
                              void* d_out, int out_size, void* d_ws, size_t ws_size,
                              hipStream_t stream) {
    const float* img = (const float*)d_in[0];
    const float* l0f = (const float*)d_in[1];
    const float* l0m = (const float*)d_in[2];
    const float* l0l = (const float*)d_in[3];
    const float* l1f = (const float*)d_in[4];
    const float* l1m = (const float*)d_in[5];
    const float* l1l = (const float*)d_in[6];
    const float* ff  = (const float*)d_in[7];
    const float* fm  = (const float*)d_in[8];
    const float* fl  = (const float*)d_in[9];
    float* out  = (float*)d_out;
    float* out0 = (float*)d_ws;        // 729 floats
    float* out1 = out0 + 729;          // 27 floats

    mps_layer_kernel<<<729, 64, 0, stream>>>(img,  l0f, l0m, l0l, out0, 9, 729);
    mps_layer_kernel<<<27,  64, 0, stream>>>(out0, l1f, l1m, l1l, out1, 3, 27);
    mps_final_kernel<<<1,   64, 0, stream>>>(out1, ff,  fm,  fl,  out);
}

// Round 6
// 278.218 us; speedup vs baseline: 1.0169x; 1.0169x over previous
//
#include <hip/hip_runtime.h>
#include <math.h>

#define NSITES 27
#define NMID   25
#define DD     32

// Load one mid-site tensor (site S) into an 8-float4 register buffer.
// m4 = per-chain base + lane; float4 index lane + 64*k ->
// (d = (lane>>4)+4k, p = (lane>>3)&1, e = 4*(lane&7)).
#define LOADB(BUF, S)                                                   \
    {                                                                   \
        const float4* pm_ = m4 + (size_t)(S) * 512;                     \
        _Pragma("unroll")                                               \
        for (int k = 0; k < 8; ++k) BUF[k] = pm_[64 * k];               \
    }

// Round-1 site body + leading barrier (compiler memory fence: orders the
// previous site's sV4 float4-store against this site's scalar sV loads).
#define COMPUTE(BUF, EI)                                                \
    {                                                                   \
        __syncthreads();                                                \
        const float e0_ = sE[EI][0];                                    \
        const float e1_ = sE[EI][1];                                    \
        float4 acc; acc.x = acc.y = acc.z = acc.w = 0.f;                \
        _Pragma("unroll")                                               \
        for (int k = 0; k < 8; ++k) {                                   \
            const float vd = sV[dbase + 4 * k];                         \
            acc.x = fmaf(BUF[k].x, vd, acc.x);                          \
            acc.y = fmaf(BUF[k].y, vd, acc.y);                          \
            acc.z = fmaf(BUF[k].z, vd, acc.z);                          \
            acc.w = fmaf(BUF[k].w, vd, acc.w);                          \
        }                                                               \
        _Pragma("unroll")                                               \
        for (int mask = 16; mask <= 32; mask <<= 1) {                   \
            acc.x += __shfl_xor(acc.x, mask, 64);                       \
            acc.y += __shfl_xor(acc.y, mask, 64);                       \
            acc.z += __shfl_xor(acc.z, mask, 64);                       \
            acc.w += __shfl_xor(acc.w, mask, 64);                       \
        }                                                               \
        float4 oth;                                                     \
        oth.x = __shfl_xor(acc.x, 8, 64);                               \
        oth.y = __shfl_xor(acc.y, 8, 64);                               \
        oth.z = __shfl_xor(acc.z, 8, 64);                               \
        oth.w = __shfl_xor(acc.w, 8, 64);                               \
        const float cm = p ? e1_ : e0_;                                 \
        const float co = p ? e0_ : e1_;                                 \
        float4 nv;                                                      \
        nv.x = fmaf(cm, acc.x, co * oth.x);                             \
        nv.y = fmaf(cm, acc.y, co * oth.y);                             \
        nv.z = fmaf(cm, acc.z, co * oth.z);                             \
        nv.w = fmaf(cm, acc.w, co * oth.w);                             \
        if (lane < 8) sV4[lane] = nv;                                   \
    }

// One wave per MPS chain; three rotating site buffers (b0,b1,b2), loads for
// site m+3 issued right after site m is consumed -> ~24 KB in flight/wave.
__global__ __launch_bounds__(64) void mps_layer_kernel(
    const float* __restrict__ src,    // cube of side 3*B
    const float* __restrict__ first,  // (N,2,1,32)
    const float* __restrict__ mid,    // (N,25,32,2,32)
    const float* __restrict__ last,   // (N,32,2)
    float*       __restrict__ out,    // (N)
    int B, int nChains)
{
    const int lane = threadIdx.x;
    const int n = blockIdx.x;
    if (n >= nChains) return;

    __shared__ float  sE[NSITES][2];
    __shared__ float4 sV4[8];
    float* sV = (float*)sV4;

    const int S = 3 * B;
    const int bh = n / (B * B);
    const int bv = (n / B) % B;
    const int bd = n % B;

    if (lane < NSITES) {
        const int kh = lane / 9, kv = (lane / 3) % 3, kd = lane % 3;
        const float x = src[(size_t)(bh*3 + kh) * S * S + (bv*3 + kv) * S + (bd*3 + kd)];
        float sn, cs;
        sincosf(1.5707963267948966f * x, &sn, &cs);
        sE[lane][0] = cs;
        sE[lane][1] = sn;
    }
    __syncthreads();
    if (lane < DD) {
        const float* f = first + (size_t)n * (2 * DD);
        sV[lane] = fmaf(f[lane], sE[0][0], f[DD + lane] * sE[0][1]);
    }

    const int p     = (lane >> 3) & 1;
    const int dbase = lane >> 4;
    const float4* m4 = (const float4*)(mid + (size_t)n * NMID * 2048) + lane;

    float4 b0[8], b1[8], b2[8];
    LOADB(b0, 0)
    LOADB(b1, 1)
    LOADB(b2, 2)

    // sites 0..23 in groups of 3; site s lives in b{s%3}, uses sE[s+1]
    for (int m = 0; m < 24; m += 3) {
        COMPUTE(b0, m + 1)
        if (m + 3 < NMID) LOADB(b0, m + 3)
        COMPUTE(b1, m + 2)
        if (m + 4 < NMID) LOADB(b1, m + 4)
        COMPUTE(b2, m + 3)
        if (m + 5 < NMID) LOADB(b2, m + 5)
    }
    // tail: site 24 (24 % 3 == 0 -> b0), embedding sE[25]
    COMPUTE(b0, 25)
    __syncthreads();

    // last site
    const float le0 = sE[26][0], le1 = sE[26][1];
    float tacc = 0.f;
    if (lane < DD) {
        const float* L = last + (size_t)n * (DD * 2);
        tacc = sV[lane] * fmaf(L[2 * lane], le0, L[2 * lane + 1] * le1);
    }
#pragma unroll
    for (int mask = 1; mask < 64; mask <<= 1) tacc += __shfl_xor(tacc, mask, 64);
    if (lane == 0) out[n] = tacc;
}

// Final layer: round-1 verbatim (passed). Output leg (O=10) on site 0 ->
// contract right-to-left: u = last*e26; u <- M_m u; out[o] = ffirst.e0.u.
__global__ __launch_bounds__(64) void mps_final_kernel(
    const float* __restrict__ x,       // out1 (27)
    const float* __restrict__ ffirst,  // (2,10,32)
    const float* __restrict__ fmid,    // (25,32,2,32)
    const float* __restrict__ flast,   // (32,2)
    float*       __restrict__ out)     // (10)
{
    const int lane = threadIdx.x;
    __shared__ float sE[NSITES][2];
    __shared__ float sU[DD];

    if (lane < NSITES) {
        float sn, cs;
        sincosf(1.5707963267948966f * x[lane], &sn, &cs);
        sE[lane][0] = cs;
        sE[lane][1] = sn;
    }
    if (lane < DD) {
        sU[lane] = fmaf(flast[2 * lane], sE[26][0], flast[2 * lane + 1] * sE[26][1]);
    }

    const int p     = (lane >> 3) & 1;
    const int e4    = lane & 7;
    const int dbase = lane >> 4;
    const float4* m4 = (const float4*)fmid + lane;

    for (int m = NMID - 1; m >= 0; --m) {
        const float e0 = sE[m + 1][0];
        const float e1 = sE[m + 1][1];
        const float ep = p ? e1 : e0;
        const float4* mm = m4 + (size_t)m * 512;

        const float4 u4 = ((const float4*)sU)[e4];
        const float wx = ep * u4.x, wy = ep * u4.y, wz = ep * u4.z, ww = ep * u4.w;

        float acc[8];
#pragma unroll
        for (int k = 0; k < 8; ++k) {
            const float4 Mv = mm[64 * k];
            acc[k] = fmaf(Mv.x, wx, fmaf(Mv.y, wy, fmaf(Mv.z, wz, Mv.w * ww)));
        }
        // full u'[d] needs sum over the 16 lanes sharing (lane>>4)
#pragma unroll
        for (int mask = 1; mask <= 8; mask <<= 1) {
#pragma unroll
            for (int k = 0; k < 8; ++k) acc[k] += __shfl_xor(acc[k], mask, 64);
        }
        if ((lane & 15) == 0) {
#pragma unroll
            for (int k = 0; k < 8; ++k) sU[dbase + 4 * k] = acc[k];
        }
    }

    const float e0 = sE[0][0], e1 = sE[0][1];
    const float ud = (lane < DD) ? sU[lane] : 0.f;
#pragma unroll
    for (int o = 0; o < 10; ++o) {
        float t = 0.f;
        if (lane < DD)
            t = fmaf(ffirst[o * DD + lane], e0, ffirst[320 + o * DD + lane] * e1) * ud;
#pragma unroll
        for (int mask = 1; mask < 64; mask <<= 1) t += __shfl_xor(t, mask, 64);
        if (lane == 0) out[o] = t;
    }
}

extern "C" void kernel_launch(void* const* d_in, const int* in_sizes, int n_in,
                              void* d_out, int out_size, void* d_ws, size_t ws_size,
                              hipStream_t stream) {
    const float* img = (const float*)d_in[0];
    const float* l0f = (const float*)d_in[1];
    const float* l0m = (const float*)d_in[2];
    const float* l0l = (const float*)d_in[3];
    const float* l1f = (const float*)d_in[4];
    const float* l1m = (const float*)d_in[5];
    const float* l1l = (const float*)d_in[6];
    const float* ff  = (const float*)d_in[7];
    const float* fm  = (const float*)d_in[8];
    const float* fl  = (const float*)d_in[9];
    float* out  = (float*)d_out;
    float* out0 = (float*)d_ws;        // 729 floats
    float* out1 = out0 + 729;          // 27 floats

    mps_layer_kernel<<<729, 64, 0, stream>>>(img,  l0f, l0m, l0l, out0, 9, 729);
    mps_layer_kernel<<<27,  64, 0, stream>>>(out0, l1f, l1m, l1l, out1, 3, 27);
    mps_final_kernel<<<1,   64, 0, stream>>>(out1, ff,  fm,  fl,  out);
}

// Round 8
// 270.051 us; speedup vs baseline: 1.0477x; 1.0302x over previous
//
#include <hip/hip_runtime.h>
#include <math.h>

#define NSITES 27
#define NMID   25
#define DD     32

// Compiler memory fence + LDS-completion wait. Unlike __syncthreads() this
// does NOT drain vmcnt, so global prefetch loads stay in flight. One wave
// per block -> no s_barrier needed; lanes are lockstep, we only need (a) the
// compiler not to reorder/cache LDS accesses across this point ("memory"
// clobber) and (b) prior ds_writes complete (lgkmcnt(0)).
#define FENCE asm volatile("s_waitcnt lgkmcnt(0)" ::: "memory");

// Load one mid-site tensor (site S) into an 8-float4 register buffer.
// m4 = per-chain base + lane; float4 index lane + 64*k ->
// (d = (lane>>4)+4k, p = (lane>>3)&1, e = 4*(lane&7)).
#define LOADB(BUF, S)                                                   \
    {                                                                   \
        const float4* pm_ = m4 + (size_t)(S) * 512;                     \
        _Pragma("unroll")                                               \
        for (int k = 0; k < 8; ++k) BUF[k] = pm_[64 * k];               \
    }

// R6-verbatim site body, with the leading __syncthreads() replaced by FENCE.
#define COMPUTE(BUF, EI)                                                \
    {                                                                   \
        FENCE                                                           \
        const float e0_ = sE[EI][0];                                    \
        const float e1_ = sE[EI][1];                                    \
        float4 acc; acc.x = acc.y = acc.z = acc.w = 0.f;                \
        _Pragma("unroll")                                               \
        for (int k = 0; k < 8; ++k) {                                   \
            const float vd = sV[dbase + 4 * k];                         \
            acc.x = fmaf(BUF[k].x, vd, acc.x);                          \
            acc.y = fmaf(BUF[k].y, vd, acc.y);                          \
            acc.z = fmaf(BUF[k].z, vd, acc.z);                          \
            acc.w = fmaf(BUF[k].w, vd, acc.w);                          \
        }                                                               \
        _Pragma("unroll")                                               \
        for (int mask = 16; mask <= 32; mask <<= 1) {                   \
            acc.x += __shfl_xor(acc.x, mask, 64);                       \
            acc.y += __shfl_xor(acc.y, mask, 64);                       \
            acc.z += __shfl_xor(acc.z, mask, 64);                       \
            acc.w += __shfl_xor(acc.w, mask, 64);                       \
        }                                                               \
        float4 oth;                                                     \
        oth.x = __shfl_xor(acc.x, 8, 64);                               \
        oth.y = __shfl_xor(acc.y, 8, 64);                               \
        oth.z = __shfl_xor(acc.z, 8, 64);                               \
        oth.w = __shfl_xor(acc.w, 8, 64);                               \
        const float cm = p ? e1_ : e0_;                                 \
        const float co = p ? e0_ : e1_;                                 \
        float4 nv;                                                      \
        nv.x = fmaf(cm, acc.x, co * oth.x);                             \
        nv.y = fmaf(cm, acc.y, co * oth.y);                             \
        nv.z = fmaf(cm, acc.z, co * oth.z);                             \
        nv.w = fmaf(cm, acc.w, co * oth.w);                             \
        if (lane < 8) sV4[lane] = nv;                                   \
    }

// One wave per MPS chain; three rotating site buffers, loads for site m+3
// issued right after site m is consumed; lgkm-only fences keep them in flight.
__global__ __launch_bounds__(64) void mps_layer_kernel(
    const float* __restrict__ src,    // cube of side 3*B
    const float* __restrict__ first,  // (N,2,1,32)
    const float* __restrict__ mid,    // (N,25,32,2,32)
    const float* __restrict__ last,   // (N,32,2)
    float*       __restrict__ out,    // (N)
    int B, int nChains)
{
    const int lane = threadIdx.x;
    const int n = blockIdx.x;
    if (n >= nChains) return;

    __shared__ float  sE[NSITES][2];
    __shared__ float4 sV4[8];
    float* sV = (float*)sV4;

    const int S = 3 * B;
    const int bh = n / (B * B);
    const int bv = (n / B) % B;
    const int bd = n % B;

    if (lane < NSITES) {
        const int kh = lane / 9, kv = (lane / 3) % 3, kd = lane % 3;
        const float x = src[(size_t)(bh*3 + kh) * S * S + (bv*3 + kv) * S + (bd*3 + kd)];
        float sn, cs;
        sincosf(1.5707963267948966f * x, &sn, &cs);
        sE[lane][0] = cs;
        sE[lane][1] = sn;
    }
    FENCE
    if (lane < DD) {
        const float* f = first + (size_t)n * (2 * DD);
        sV[lane] = fmaf(f[lane], sE[0][0], f[DD + lane] * sE[0][1]);
    }

    const int p     = (lane >> 3) & 1;
    const int dbase = lane >> 4;
    const float4* m4 = (const float4*)(mid + (size_t)n * NMID * 2048) + lane;

    float4 b0[8], b1[8], b2[8];
    LOADB(b0, 0)
    LOADB(b1, 1)
    LOADB(b2, 2)

    // sites 0..23 in groups of 3; site s lives in b{s%3}, uses sE[s+1]
    for (int m = 0; m < 24; m += 3) {
        COMPUTE(b0, m + 1)
        if (m + 3 < NMID) LOADB(b0, m + 3)
        COMPUTE(b1, m + 2)
        if (m + 4 < NMID) LOADB(b1, m + 4)
        COMPUTE(b2, m + 3)
        if (m + 5 < NMID) LOADB(b2, m + 5)
    }
    // tail: site 24 (24 % 3 == 0 -> b0), embedding sE[25]
    COMPUTE(b0, 25)
    FENCE

    // last site
    const float le0 = sE[26][0], le1 = sE[26][1];
    float tacc = 0.f;
    if (lane < DD) {
        const float* L = last + (size_t)n * (DD * 2);
        tacc = sV[lane] * fmaf(L[2 * lane], le0, L[2 * lane + 1] * le1);
    }
#pragma unroll
    for (int mask = 1; mask < 64; mask <<= 1) tacc += __shfl_xor(tacc, mask, 64);
    if (lane == 0) out[n] = tacc;
}

// Final-layer site step (right-to-left): u'[d] = sum_{e,p} e_p M[d][p][e] u[e].
#define FSITE(BUF, M)                                                   \
    {                                                                   \
        FENCE                                                           \
        const float e0_ = sE[(M) + 1][0];                               \
        const float e1_ = sE[(M) + 1][1];                               \
        const float ep_ = p ? e1_ : e0_;                                \
        const float4 u4 = ((const float4*)sU)[e4];                      \
        const float wx = ep_ * u4.x, wy = ep_ * u4.y;                   \
        const float wz = ep_ * u4.z, ww = ep_ * u4.w;                   \
        float acc[8];                                                   \
        _Pragma("unroll")                                               \
        for (int k = 0; k < 8; ++k) {                                   \
            const float4 Mv = BUF[k];                                   \
            acc[k] = fmaf(Mv.x, wx, fmaf(Mv.y, wy, fmaf(Mv.z, wz, Mv.w * ww))); \
        }                                                               \
        _Pragma("unroll")                                               \
        for (int mask = 1; mask <= 8; mask <<= 1) {                     \
            _Pragma("unroll")                                           \
            for (int k = 0; k < 8; ++k) acc[k] += __shfl_xor(acc[k], mask, 64); \
        }                                                               \
        if ((lane & 15) == 0) {                                         \
            _Pragma("unroll")                                           \
            for (int k = 0; k < 8; ++k) sU[dbase + 4 * k] = acc[k];     \
        }                                                               \
    }

// Final layer: output leg (O=10) on site 0 -> contract right-to-left with the
// same rotating 3-buffer prefetch. u = last*e26; u <- M_m u (m=24..0);
// out[o] = sum_{p,d} ffirst[p][o][d] e0_p u[d].
__global__ __launch_bounds__(64) void mps_final_kernel(
    const float* __restrict__ x,       // out1 (27)
    const float* __restrict__ ffirst,  // (2,10,32)
    const float* __restrict__ fmid,    // (25,32,2,32)
    const float* __restrict__ flast,   // (32,2)
    float*       __restrict__ out)     // (10)
{
    const int lane = threadIdx.x;
    __shared__ float sE[NSITES][2];
    __shared__ float sU[DD];

    if (lane < NSITES) {
        float sn, cs;
        sincosf(1.5707963267948966f * x[lane], &sn, &cs);
        sE[lane][0] = cs;
        sE[lane][1] = sn;
    }
    FENCE
    if (lane < DD) {
        sU[lane] = fmaf(flast[2 * lane], sE[26][0], flast[2 * lane + 1] * sE[26][1]);
    }

    const int p     = (lane >> 3) & 1;
    const int e4    = lane & 7;
    const int dbase = lane >> 4;
    const float4* m4 = (const float4*)fmid + lane;

    float4 c0[8], c1[8], c2[8];
    LOADB(c0, 24)
    LOADB(c1, 23)
    LOADB(c2, 22)

    // iterations t=0..7 consume sites 24-3t, 23-3t, 22-3t (24..1); tail site 0.
    for (int t = 0; t < 8; ++t) {
        const int s0 = 24 - 3 * t;
        FSITE(c0, s0)
        if (s0 - 3 >= 0) LOADB(c0, s0 - 3)     // next c0 site (t=7 loads site 0)
        FSITE(c1, s0 - 1)
        if (s0 - 4 >= 0) LOADB(c1, s0 - 4)
        FSITE(c2, s0 - 2)
        if (s0 - 5 >= 0) LOADB(c2, s0 - 5)
    }
    // tail: site 0 (in c0), embedding sE[1]
    FSITE(c0, 0)
    FENCE

    const float e0 = sE[0][0], e1 = sE[0][1];
    const float ud = (lane < DD) ? sU[lane] : 0.f;
#pragma unroll
    for (int o = 0; o < 10; ++o) {
        float t = 0.f;
        if (lane < DD)
            t = fmaf(ffirst[o * DD + lane], e0, ffirst[320 + o * DD + lane] * e1) * ud;
#pragma unroll
        for (int mask = 1; mask < 64; mask <<= 1) t += __shfl_xor(t, mask, 64);
        if (lane == 0) out[o] = t;
    }
}

extern "C" void kernel_launch(void* const* d_in, const int* in_sizes, int n_in,
                              void* d_out, int out_size, void* d_ws, size_t ws_size,
                              hipStream_t stream) {
    const float* img = (const float*)d_in[0];
    const float* l0f = (const float*)d_in[1];
    const float* l0m = (const float*)d_in[2];
    const float* l0l = (const float*)d_in[3];
    const float* l1f = (const float*)d_in[4];
    const float* l1m = (const float*)d_in[5];
    const float* l1l = (const float*)d_in[6];
    const float* ff  = (const float*)d_in[7];
    const float* fm  = (const float*)d_in[8];
    const float* fl  = (const float*)d_in[9];
    float* out  = (float*)d_out;
    float* out0 = (float*)d_ws;        // 729 floats
    float* out1 = out0 + 729;          // 27 floats

    mps_layer_kernel<<<729, 64, 0, stream>>>(img,  l0f, l0m, l0l, out0, 9, 729);
    mps_layer_kernel<<<27,  64, 0, stream>>>(out0, l1f, l1m, l1l, out1, 3, 27);
    mps_final_kernel<<<1,   64, 0, stream>>>(out1, ff,  fm,  fl,  out);
}